// Round 4
// baseline (776.994 us; speedup 1.0000x reference)
//
#include <hip/hip_runtime.h>
#include <hip/hip_bf16.h>
#include <math.h>

#define B_ 32
#define S_ 128
#define C_ 384
#define H_ 8
#define W_ 512
#define NKV 4096   // H_*W_

typedef __attribute__((ext_vector_type(8))) short short8;
typedef __attribute__((ext_vector_type(4))) float floatx4;

static __device__ __forceinline__ ushort f2bf(float v) {
    __hip_bfloat16 h = __float2bfloat16(v);
    return *(ushort*)&h;
}
static __device__ __forceinline__ float ldf(const float* p, size_t i) { return p[i]; }
static __device__ __forceinline__ float ldf(const ushort* p, size_t i) {
    union { uint u; float f; } c; c.u = (uint)p[i] << 16; return c.f;
}

// ---------------------------------------------------------------- mean over H -> bf16
__global__ __launch_bounds__(256) void mean_kernel(const float* __restrict__ kv,
                                                   ushort* __restrict__ dec0b) {
    int v = blockIdx.x * blockDim.x + threadIdx.x;
    int total = B_ * W_ * (C_ / 4);
    if (v >= total) return;
    int c4  = v % (C_ / 4);
    int row = v / (C_ / 4);
    int b = row / W_;
    int w = row % W_;
    const float4* src = (const float4*)kv + (size_t)(b * NKV + w) * (C_ / 4) + c4;
    float4 s = {0.f, 0.f, 0.f, 0.f};
#pragma unroll
    for (int h = 0; h < H_; ++h) {
        float4 t = src[(size_t)h * W_ * (C_ / 4)];
        s.x += t.x; s.y += t.y; s.z += t.z; s.w += t.w;
    }
    ushort4 o;
    o.x = f2bf(s.x * 0.125f); o.y = f2bf(s.y * 0.125f);
    o.z = f2bf(s.z * 0.125f); o.w = f2bf(s.w * 0.125f);
    ((ushort4*)dec0b)[v] = o;
}

// --------------------------------- 13-job weight transpose+cast / q identity-cast
struct WtD2 { const float* src[13]; ushort* dst[13]; int off[14]; };
__global__ __launch_bounds__(256) void wtcast_kernel(WtD2 d) {
    int gid = blockIdx.x * 256 + threadIdx.x;
    if (gid >= d.off[13]) return;
    int j = 0;
    while (j < 12 && gid >= d.off[j + 1]) ++j;
    int idx = gid - d.off[j];
    if (j == 12) { d.dst[12][idx] = f2bf(d.src[12][idx]); return; }
    const int K = 384;
    int N = (j >= 9) ? 768 : 384;
    int n = idx / K, k = idx - n * K;
    d.dst[j][idx] = f2bf(d.src[j][(size_t)k * N + n]);
}

// ---------------------------------------------------------------- bf16 MFMA GEMM 128x128
// normal: Cout/Cbf. kv-split: col<384 -> kdst (ld 384); col>=384 -> vtdst transposed (B,384,nw).
__global__ __launch_bounds__(256) void bgemm_kernel(
    const ushort* __restrict__ A, const ushort* __restrict__ Bt,
    const float* __restrict__ bias, float* __restrict__ Cout,
    ushort* __restrict__ Cbf, ushort* __restrict__ kdst, ushort* __restrict__ vtdst,
    int nw, int nws, int M, int N, int K, float alpha, int act)
{
    __shared__ ushort As[128 * 40];
    __shared__ ushort Bs[128 * 40];
    const int tid = threadIdx.x;
    const int bm = blockIdx.y * 128, bn = blockIdx.x * 128;
    const int wav = tid >> 6, lane = tid & 63;
    const int wm = (wav >> 1) * 64, wn = (wav & 1) * 64;
    const int lrow = lane & 15, lq = lane >> 4;

    floatx4 acc[4][4] = {};

    const int sr = tid >> 1, sc0 = (tid & 1) * 16;
    const ushort* Ag = A + (size_t)(bm + sr) * K + sc0;
    const ushort* Bg = Bt + (size_t)(bn + sr) * K + sc0;
    ushort* Asw = &As[sr * 40 + sc0];
    ushort* Bsw = &Bs[sr * 40 + sc0];

    for (int k0 = 0; k0 < K; k0 += 32) {
        uint4 a0 = *(const uint4*)(Ag + k0);
        uint4 a1 = *(const uint4*)(Ag + k0 + 8);
        uint4 b0 = *(const uint4*)(Bg + k0);
        uint4 b1 = *(const uint4*)(Bg + k0 + 8);
        __syncthreads();
        *(uint4*)Asw = a0; *(uint4*)(Asw + 8) = a1;
        *(uint4*)Bsw = b0; *(uint4*)(Bsw + 8) = b1;
        __syncthreads();
        short8 af[4], bfr[4];
#pragma unroll
        for (int i = 0; i < 4; ++i)
            af[i] = *(const short8*)&As[(wm + 16 * i + lrow) * 40 + lq * 8];
#pragma unroll
        for (int j = 0; j < 4; ++j)
            bfr[j] = *(const short8*)&Bs[(wn + 16 * j + lrow) * 40 + lq * 8];
#pragma unroll
        for (int i = 0; i < 4; ++i)
#pragma unroll
            for (int j = 0; j < 4; ++j)
                acc[i][j] = __builtin_amdgcn_mfma_f32_16x16x32_bf16(af[i], bfr[j], acc[i][j], 0, 0, 0);
    }

#pragma unroll
    for (int i = 0; i < 4; ++i)
#pragma unroll
        for (int j = 0; j < 4; ++j) {
            int row0 = bm + wm + 16 * i + lq * 4;
            int col = bn + wn + 16 * j + lrow;
            float bv = bias ? bias[col] : 0.f;
#pragma unroll
            for (int r = 0; r < 4; ++r) {
                float v = acc[i][j][r] * alpha + bv;
                if (act == 1) v = tanhf(v);
                int row = row0 + r;
                if (kdst) {
                    int b = row >> nws, w = row & (nw - 1);
                    if (col < 384) kdst[(size_t)row * 384 + col] = f2bf(v);
                    else vtdst[((size_t)b * 384 + (col - 384)) * (size_t)nw + w] = f2bf(v);
                } else {
                    size_t off = (size_t)row * N + col;
                    if (Cout) Cout[off] = v;
                    if (Cbf) Cbf[off] = f2bf(v);
                }
            }
        }
}

// ------------------------------------------- generic batched 64x64 MFMA GEMM
// mode 0: normal (bias/act/gauss epilogue, outF/outB)
// mode 1: split384 (cols<384 -> outS bf16; cols>=384 -> outF fp32 + bias[col-384])
// mode 2: softpv  (A = fp32 scores, per-row softmax applied during staging)
struct BGArgs {
    const ushort* A; const float* Af; const ushort* Bt;
    const float* bias; float* outF; ushort* outB; ushort* outS;
    int lda, ldb, ldo;
    long AsB, BsB, OsB;
    int AsH, BsH, OsH;
    int K, NH;
    float alpha; int act; int mode; int gauss;
    const float* ptv;
};
__global__ __launch_bounds__(256) void battn_kernel(BGArgs g) {
    __shared__ ushort As[64 * 40];
    __shared__ ushort Bs[64 * 40];
    __shared__ float rowm[64], rowr[64];
    const int bn = blockIdx.x * 64, bm = blockIdx.y * 64;
    const int bat = blockIdx.z, bb = bat / g.NH, hh = bat % g.NH;
    const int tid = threadIdx.x;
    const int wav = tid >> 6, lane = tid & 63;
    const int lrow = lane & 15, lq = lane >> 4;
    const int sr = tid >> 2, sc0 = (tid & 3) * 8;

    const ushort* Bg = g.Bt + (size_t)bb * g.BsB + (size_t)hh * g.BsH
                     + (size_t)(bn + sr) * g.ldb + sc0;
    ushort* Asw = &As[sr * 40 + sc0];
    ushort* Bsw = &Bs[sr * 40 + sc0];

    const ushort* Ag = nullptr;
    const float* Agf = nullptr;
    if (g.mode == 2) {
        const float* base = g.Af + (size_t)bb * g.AsB + (size_t)hh * g.AsH;
        Agf = base + (size_t)(bm + sr) * g.lda + sc0;
        for (int r = wav; r < 64; r += 4) {
            const float* srow = base + (size_t)(bm + r) * g.lda;
            float mx = -1e30f;
            for (int c = lane; c < g.K; c += 64) mx = fmaxf(mx, srow[c]);
#pragma unroll
            for (int o = 32; o; o >>= 1) mx = fmaxf(mx, __shfl_xor(mx, o));
            float sm = 0.f;
            for (int c = lane; c < g.K; c += 64) sm += expf(srow[c] - mx);
#pragma unroll
            for (int o = 32; o; o >>= 1) sm += __shfl_xor(sm, o);
            if (lane == 0) { rowm[r] = mx; rowr[r] = 1.0f / sm; }
        }
        __syncthreads();
    } else {
        Ag = g.A + (size_t)bb * g.AsB + (size_t)hh * g.AsH
           + (size_t)(bm + sr) * g.lda + sc0;
    }

    floatx4 acc[4] = {};

    for (int k0 = 0; k0 < g.K; k0 += 32) {
        uint4 b = *(const uint4*)(Bg + k0);
        union { ushort us[8]; uint4 v; } ap;
        if (g.mode == 2) {
            float4 f0 = *(const float4*)(Agf + k0);
            float4 f1 = *(const float4*)(Agf + k0 + 4);
            float m = rowm[sr], rv = rowr[sr];
            ap.us[0] = f2bf(expf(f0.x - m) * rv);
            ap.us[1] = f2bf(expf(f0.y - m) * rv);
            ap.us[2] = f2bf(expf(f0.z - m) * rv);
            ap.us[3] = f2bf(expf(f0.w - m) * rv);
            ap.us[4] = f2bf(expf(f1.x - m) * rv);
            ap.us[5] = f2bf(expf(f1.y - m) * rv);
            ap.us[6] = f2bf(expf(f1.z - m) * rv);
            ap.us[7] = f2bf(expf(f1.w - m) * rv);
        } else {
            ap.v = *(const uint4*)(Ag + k0);
        }
        __syncthreads();
        *(uint4*)Asw = ap.v;
        *(uint4*)Bsw = b;
        __syncthreads();
        short8 af = *(const short8*)&As[(wav * 16 + lrow) * 40 + lq * 8];
#pragma unroll
        for (int j = 0; j < 4; ++j) {
            short8 bf = *(const short8*)&Bs[(16 * j + lrow) * 40 + lq * 8];
            acc[j] = __builtin_amdgcn_mfma_f32_16x16x32_bf16(af, bf, acc[j], 0, 0, 0);
        }
    }

#pragma unroll
    for (int j = 0; j < 4; ++j) {
        int col = bn + 16 * j + lrow;
        int row0 = bm + wav * 16 + lq * 4;
#pragma unroll
        for (int r = 0; r < 4; ++r) {
            float v = acc[j][r] * g.alpha;
            int row = row0 + r;
            if (g.mode == 1) {
                if (col < 384) g.outS[(size_t)row * 384 + col] = f2bf(v);
                else g.outF[(size_t)row * 384 + (col - 384)] = v + g.bias[col - 384];
                continue;
            }
            if (g.bias) v += g.bias[col];
            if (g.act == 1) v = tanhf(v);
            if (g.gauss) {
                float dw = (float)col - g.ptv[bb * S_ + row];
                v *= expf(dw * dw * (-1.0f / 18.0f));
            }
            size_t off = (size_t)bb * g.OsB + (size_t)hh * g.OsH
                       + (size_t)row * g.ldo + col;
            if (g.outF) g.outF[off] = v;
            if (g.outB) g.outB[off] = f2bf(v);
        }
    }
}

static inline void battn(hipStream_t st, const ushort* A, const float* Af,
                         const ushort* Bt, const float* bias,
                         float* outF, ushort* outB, ushort* outS,
                         int M, int N, int K, float alpha, int act, int mode, int gauss,
                         const float* ptv,
                         int lda, long AsB, int AsH,
                         int ldb, long BsB, int BsH,
                         int ldo, long OsB, int OsH,
                         int NH, int nbat) {
    BGArgs g;
    g.A = A; g.Af = Af; g.Bt = Bt; g.bias = bias;
    g.outF = outF; g.outB = outB; g.outS = outS;
    g.lda = lda; g.ldb = ldb; g.ldo = ldo;
    g.AsB = AsB; g.BsB = BsB; g.OsB = OsB;
    g.AsH = AsH; g.BsH = BsH; g.OsH = OsH;
    g.K = K; g.NH = NH; g.alpha = alpha; g.act = act; g.mode = mode;
    g.gauss = gauss; g.ptv = ptv;
    dim3 grid(N / 64, M / 64, nbat);
    battn_kernel<<<grid, 256, 0, st>>>(g);
}

static inline void bgemm64(hipStream_t st, const ushort* A, const ushort* Bt,
                           const float* bias, float* outF, ushort* outB,
                           int M, int N, int K, float alpha, int act) {
    battn(st, A, nullptr, Bt, bias, outF, outB, nullptr, M, N, K, alpha, act, 0, 0,
          nullptr, K, 0, 0, K, 0, 0, N, 0, 0, 1, 1);
}

// ---------------------------------------------------------------- dual LayerNorm -> bf16
struct LN2Args {
    const float* X1; const float* g1; const float* b1; ushort* Y1; int n1;
    const void* X2; int x2bf; const float* g2; const float* b2; ushort* Y2;
};
__global__ __launch_bounds__(128) void ln2_kernel(LN2Args a) {
    int blk = blockIdx.x;
    int t = threadIdx.x;
    float v0, v1, v2;
    const float *g, *bb; ushort* y;
    if (blk < a.n1) {
        const float* x = a.X1 + (size_t)blk * C_;
        v0 = x[t]; v1 = x[t + 128]; v2 = x[t + 256];
        g = a.g1; bb = a.b1; y = a.Y1 + (size_t)blk * C_;
    } else {
        int row = blk - a.n1;
        if (a.x2bf) {
            const ushort* x = (const ushort*)a.X2 + (size_t)row * C_;
            v0 = ldf(x, t); v1 = ldf(x, t + 128); v2 = ldf(x, t + 256);
        } else {
            const float* x = (const float*)a.X2 + (size_t)row * C_;
            v0 = x[t]; v1 = x[t + 128]; v2 = x[t + 256];
        }
        g = a.g2; bb = a.b2; y = a.Y2 + (size_t)row * C_;
    }
    float s = v0 + v1 + v2, sq = v0 * v0 + v1 * v1 + v2 * v2;
    __shared__ float rs[128], rq[128];
    rs[t] = s; rq[t] = sq; __syncthreads();
    if (t < 64) {
        s = rs[t] + rs[t + 64]; sq = rq[t] + rq[t + 64];
        for (int o = 32; o; o >>= 1) { s += __shfl_down(s, o); sq += __shfl_down(sq, o); }
        if (t == 0) { rs[0] = s; rq[0] = sq; }
    }
    __syncthreads();
    float mean = rs[0] * (1.0f / C_);
    float var  = rq[0] * (1.0f / C_) - mean * mean;
    float inv  = rsqrtf(var + 1e-6f);
    y[t]       = f2bf((v0 - mean) * inv * g[t]       + bb[t]);
    y[t + 128] = f2bf((v1 - mean) * inv * g[t + 128] + bb[t + 128]);
    y[t + 256] = f2bf((v2 - mean) * inv * g[t + 256] + bb[t + 256]);
}

// ---------------------------------------------------------------- p_t head
__global__ __launch_bounds__(128) void pt_kernel(const float* __restrict__ T,
    const float* __restrict__ vpw, const float* __restrict__ vpb,
    float* __restrict__ out) {
    int row = blockIdx.x;
    int t = threadIdx.x;
    const float* x = T + (size_t)row * C_;
    float s = x[t] * vpw[t] + x[t + 128] * vpw[t + 128] + x[t + 256] * vpw[t + 256];
    __shared__ float red[128];
    red[t] = s; __syncthreads();
    if (t < 64) {
        s = red[t] + red[t + 64];
        for (int o = 32; o; o >>= 1) s += __shfl_down(s, o);
        if (t == 0) {
            float z = s + vpb[0];
            out[row] = 512.0f / (1.0f + expf(-z));
        }
    }
}

// ---------------------------------------------------------------- launch
extern "C" void kernel_launch(void* const* d_in, const int* in_sizes, int n_in,
                              void* d_out, int out_size, void* d_ws, size_t ws_size,
                              hipStream_t stream) {
    const float* q     = (const float*)d_in[0];
    const float* kv    = (const float*)d_in[1];
    const float* Wq    = (const float*)d_in[2];
    const float* Wkv   = (const float*)d_in[3];
    const float* Wproj = (const float*)d_in[4];
    const float* bproj = (const float*)d_in[5];
    const float* Wp_w  = (const float*)d_in[6];
    const float* Wp_b  = (const float*)d_in[7];
    const float* vp_w  = (const float*)d_in[8];
    const float* vp_b  = (const float*)d_in[9];
    const float* Wqpos = (const float*)d_in[10];
    const float* bqpos = (const float*)d_in[11];
    const float* Wrctc = (const float*)d_in[12];
    const float* brctc = (const float*)d_in[13];
    const float* ca1_Wq    = (const float*)d_in[14];
    const float* ca1_Wkv   = (const float*)d_in[15];
    const float* ca1_Wproj = (const float*)d_in[16];
    const float* ca1_bproj = (const float*)d_in[17];
    const float* ca2_Wq    = (const float*)d_in[18];
    const float* ca2_Wkv   = (const float*)d_in[19];
    const float* ca2_Wproj = (const float*)d_in[20];
    const float* ca2_bproj = (const float*)d_in[21];
    const float* g_q1  = (const float*)d_in[22];
    const float* b_q1  = (const float*)d_in[23];
    const float* g_kv1 = (const float*)d_in[24];
    const float* b_kv1 = (const float*)d_in[25];
    const float* g_q2  = (const float*)d_in[26];
    const float* b_q2  = (const float*)d_in[27];
    const float* g_kv2 = (const float*)d_in[28];
    const float* b_kv2 = (const float*)d_in[29];
    float* out = (float*)d_out;
    float* ws  = (float*)d_ws;

    // workspace (float offsets)
    ushort* dec0b = (ushort*)(ws);                   // 6291456 ush
    ushort* wb    = (ushort*)(ws + 3145728);         // 2211840 ush
    ushort* qb    = (ushort*)(ws + 4251648);         // 1572864 ush
    ushort* decb  = (ushort*)(ws + 5038080);         // 6291456 ush
    ushort* qhb   = (ushort*)(ws + 8183808);         // 1572864 ush
    float*  p     = ws + 8970240;                    // 1572864 fl
    ushort* pb    = (ushort*)(ws + 10543104);        // 1572864 ush
    float*  t1    = ws + 11329536;                   // 1572864 fl
    ushort* t1b   = (ushort*)(ws + 12902400);        // 1572864 ush
    ushort* t2b   = (ushort*)(ws + 13688832);        // 6291456 ush
    ushort* qpb   = (ushort*)(ws + 16834560);        // 1572864 ush
    ushort* kb    = (ushort*)(ws + 17620992);        // 6291456 ush
    ushort* vt    = (ushort*)(ws + 20766720);        // 6291456 ush
    float*  sc    = ws + 23912448;                   // 4194304 fl
    ushort* xb    = (ushort*)(ws + 28106752);        // 1572864 ush
    float*  ptb   = ws + 28893184;                   // 4096 fl

    // bf16 transposed weights (ushort offsets in wb)
    ushort* wbQQ     = wb;                 // Wq | Wqpos combined (768 rows x 384)
    ushort* wbWrctc  = wb + 294912;
    ushort* wbC1Wq   = wb + 442368;
    ushort* wbC1Wp   = wb + 589824;
    ushort* wbC2Wq   = wb + 737280;
    ushort* wbC2Wp   = wb + 884736;
    ushort* wbWpw    = wb + 1032192;
    ushort* wbWproj  = wb + 1179648;
    ushort* wbWkv    = wb + 1327104;
    ushort* wbC1Wkv  = wb + 1622016;
    ushort* wbC2Wkv  = wb + 1916928;

    const float rs384 = 0.05103103630798288f;  // 1/sqrt(384)
    const float rs192 = 0.07216878364870323f;  // 1/sqrt(192)

    // 1. mean over H -> bf16
    mean_kernel<<<(B_ * W_ * (C_ / 4) + 255) / 256, 256, 0, stream>>>(kv, dec0b);

    // 2. weight transpose-casts + q cast (one launch, 13 jobs)
    {
        WtD2 d;
        const float* s_[13] = {Wq, Wqpos, Wrctc, ca1_Wq, ca1_Wproj, ca2_Wq, ca2_Wproj,
                               Wp_w, Wproj, Wkv, ca1_Wkv, ca2_Wkv, q};
        ushort* t_[13] = {wbQQ, wbQQ + 147456, wbWrctc, wbC1Wq, wbC1Wp, wbC2Wq, wbC2Wp,
                          wbWpw, wbWproj, wbWkv, wbC1Wkv, wbC2Wkv, qb};
        int cnt[13] = {147456,147456,147456,147456,147456,147456,147456,147456,147456,
                       294912,294912,294912, 1572864};
        int acc = 0;
        for (int i = 0; i < 13; ++i) { d.src[i] = s_[i]; d.dst[i] = t_[i]; d.off[i] = acc; acc += cnt[i]; }
        d.off[13] = acc;
        wtcast_kernel<<<(acc + 255) / 256, 256, 0, stream>>>(d);
    }

    // 3. merged q GEMM: cols<384 -> qhb bf16 (unscaled), cols>=384 -> p fp32 + bqpos
    battn(stream, qb, nullptr, wbQQ, bqpos, p, nullptr, qhb,
          B_ * S_, 768, 384, 1.f, 0, 1, 0, nullptr,
          384, 0, 0, 384, 0, 0, 384, 0, 0, 1, 1);

    // 4. dec = dec0 @ Wrctc + brctc -> bf16
    {
        dim3 grid(384 / 128, (B_ * W_) / 128);
        bgemm_kernel<<<grid, 256, 0, stream>>>(dec0b, wbWrctc, brctc, nullptr, decb,
                                               nullptr, nullptr, 0, 0,
                                               B_ * W_, 384, 384, 1.f, 0);
    }

    // 5. ca1: LN(p)+LN(q) in one launch
    {
        LN2Args a = {p, g_q1, b_q1, t1b, B_ * S_, q, 0, g_kv1, b_kv1, t2b};
        ln2_kernel<<<2 * B_ * S_, 128, 0, stream>>>(a);
    }
    bgemm64(stream, t1b, wbC1Wq, nullptr, nullptr, qpb, B_ * S_, 384, 384, 1.f, 0);
    {
        dim3 grid(768 / 128, (B_ * S_) / 128);
        bgemm_kernel<<<grid, 256, 0, stream>>>(t2b, wbC1Wkv, nullptr, nullptr, nullptr,
                                               kb, vt, 128, 7,
                                               B_ * S_, 768, 384, 1.f, 0);
    }
    battn(stream, qpb, nullptr, kb, nullptr, sc, nullptr, nullptr,
          S_, 128, 192, rs192, 0, 0, 0, nullptr,
          384, (long)S_ * 384, 192,
          384, (long)S_ * 384, 192,
          128, (long)2 * S_ * 128, S_ * 128, 2, 64);
    battn(stream, nullptr, sc, vt, nullptr, nullptr, xb, nullptr,
          S_, 192, 128, 1.f, 0, 2, 0, nullptr,
          128, (long)2 * S_ * 128, S_ * 128,
          128, (long)C_ * S_, 192 * S_,
          384, (long)S_ * 384, 192, 2, 64);
    bgemm64(stream, xb, wbC1Wp, ca1_bproj, p, nullptr, B_ * S_, 384, 384, 1.f, 0);

    // 6. ca2: LN(p)+LN(dec bf16) in one launch
    {
        LN2Args a = {p, g_q2, b_q2, t1b, B_ * S_, decb, 1, g_kv2, b_kv2, t2b};
        ln2_kernel<<<B_ * S_ + B_ * W_, 128, 0, stream>>>(a);
    }
    bgemm64(stream, t1b, wbC2Wq, nullptr, nullptr, qpb, B_ * S_, 384, 384, 1.f, 0);
    {
        dim3 grid(768 / 128, (B_ * W_) / 128);
        bgemm_kernel<<<grid, 256, 0, stream>>>(t2b, wbC2Wkv, nullptr, nullptr, nullptr,
                                               kb, vt, 512, 9,
                                               B_ * W_, 768, 384, 1.f, 0);
    }
    battn(stream, qpb, nullptr, kb, nullptr, sc, nullptr, nullptr,
          S_, 512, 192, rs192, 0, 0, 0, nullptr,
          384, (long)S_ * 384, 192,
          384, (long)W_ * 384, 192,
          512, (long)2 * S_ * 512, S_ * 512, 2, 64);
    battn(stream, nullptr, sc, vt, nullptr, nullptr, xb, nullptr,
          S_, 192, 512, 1.f, 0, 2, 0, nullptr,
          512, (long)2 * S_ * 512, S_ * 512,
          512, (long)C_ * W_, 192 * W_,
          384, (long)S_ * 384, 192, 2, 64);
    bgemm64(stream, xb, wbC2Wp, ca2_bproj, p, pb, B_ * S_, 384, 384, 1.f, 0);

    // 7. p_t head
    bgemm64(stream, pb, wbWpw, Wp_b, t1, nullptr, B_ * S_, 384, 384, 1.f, 1);
    pt_kernel<<<B_ * S_, 128, 0, stream>>>(t1, vp_w, vp_b, ptb);

    // 8. main k/v = dec @ Wkv (split k / v^T)
    {
        dim3 grid(768 / 128, (B_ * W_) / 128);
        bgemm_kernel<<<grid, 256, 0, stream>>>(decb, wbWkv, nullptr, nullptr, nullptr,
                                               kb, vt, 512, 9,
                                               B_ * W_, 768, 384, 1.f, 0);
    }

    // 9. main attention: score GEMM (gauss fused) + PV GEMM (softmax fused)
    battn(stream, qhb, nullptr, kb, nullptr, sc, nullptr, nullptr,
          S_, 512, 384, rs384, 0, 0, 1, ptb,
          384, (long)S_ * 384, 0,
          384, (long)W_ * 384, 0,
          512, (long)S_ * 512, 0, 1, 32);
    battn(stream, nullptr, sc, vt, nullptr, nullptr, xb, nullptr,
          S_, 384, 512, 1.f, 0, 2, 0, nullptr,
          512, (long)S_ * 512, 0,
          512, (long)C_ * W_, 0,
          384, (long)S_ * 384, 0, 1, 32);

    // 10. out = x @ Wproj + bproj (fp32)
    bgemm64(stream, xb, wbWproj, bproj, out, nullptr, B_ * S_, 384, 384, 1.f, 0);
}